// Round 6
// baseline (331.939 us; speedup 1.0000x reference)
//
#include <hip/hip_runtime.h>

// VQ via MFMA: x (32,64,64,64) fp32 NCHW, embed (512,64) fp32.
// fp16 MFMA approx dists (err ~0.18 << EPS 0.5), exact fp32 recheck of
// near-min candidates (bit-identical dot+esq formulas) -> exact argmin.
//
// R17 post-mortem: 8x fewer blocks + 1 dispatch + zero-mem hot loop ->
// 69->65us only. Combined with R15/R16: wall is invariant to occupancy
// (18-67%), MFMA count, codebook residency, block count. All pipes <30%.
// Per-tile wall ~19.5k cyc vs ~4-5k modeled -> the per-tile latency chain
// (stage-load waited at tile top + 3 barrier drains, zero cross-tile
// overlap) is the remaining structural suspect.
//
// R18: pipeline the tile loop.
//  - T14 async-stage: tile t+1's 8 x-loads issued at top of tile t into
//    regs P[8]; written to LDS next iter (latency cover ~4k cyc vs 0).
//  - double-buffer XsH/Xs32 + row_best/qcnt -> barrier 3 DELETED
//    (2 barriers/tile); next stage-write never waits on prev epilogue.
//  - TILES 8->4, grid 1024, launch_bounds(256,4): 4 blocks/CU co-resident
//    (VGPR cap 128 = R17's measured count; LDS 30.8KB), clean TLP re-test
//    without R16's spill confound.
//  - esq regs -> per-use LDS reads; prologue esq/B-frag loads float4-ized
//    (exact fmaf order kept) to fund the 8 P-regs.
// Predict: VGPR<=128, WRITE ~33.3MB (spill tripwire), LDS ~31KB,
// Occupancy -> 45-55%, dur 65 -> 40-48us. If dur ~65 unchanged -> no
// source-visible overlap lever remains; next round = phase ablation.

#define VQ_N 131072
#define VQ_D 64
#define VQ_K 512
#define VQ_HW 4096
#define ROWS 32          // rows per tile
#define TILES 4          // row-tiles per block; grid = N/(ROWS*TILES) = 1024
#define EPS 0.5f         // prune margin; fp16 worst-case err ~0.18, typ ~0.01
#define QW 256           // queue entries per wave (slots 0..31 = row winners)
#define XH_STR 72        // f16/row (64+8 pad), 144B stride (16B-aligned)
#define X32_STR 69       // floats/row: ODD -> conflict-free staging writes

typedef __attribute__((ext_vector_type(8))) _Float16 half8;
typedef __attribute__((ext_vector_type(4))) float f32x4;

// order-preserving float->uint for the exact-recheck u64 key
static __device__ __forceinline__ unsigned fenc(float f) {
    unsigned u = __float_as_uint(f);
    return u ^ ((unsigned)(((int)u) >> 31) | 0x80000000u);
}
// clear low 9 mantissa bits (decode of embedded-index float keys)
static __device__ __forceinline__ float clr9(float f) {
    return __uint_as_float(__float_as_uint(f) & 0xFFFFFE00u);
}

// build B fragment pair for code-tile nt from embed fp32 (RTE casts)
#define LOADBF(nt, F0, F1) {                                                   \
    const float* _er = embed + (size_t)(nb + ((nt) << 4) + lrow) * VQ_D        \
                       + (quad << 3);                                          \
    float4 _a = *(const float4*)_er;                                           \
    float4 _b2 = *(const float4*)(_er + 4);                                    \
    float4 _c = *(const float4*)(_er + 32);                                    \
    float4 _d2 = *(const float4*)(_er + 36);                                   \
    F0[0] = (_Float16)_a.x;  F0[1] = (_Float16)_a.y;                           \
    F0[2] = (_Float16)_a.z;  F0[3] = (_Float16)_a.w;                           \
    F0[4] = (_Float16)_b2.x; F0[5] = (_Float16)_b2.y;                          \
    F0[6] = (_Float16)_b2.z; F0[7] = (_Float16)_b2.w;                          \
    F1[0] = (_Float16)_c.x;  F1[1] = (_Float16)_c.y;                           \
    F1[2] = (_Float16)_c.z;  F1[3] = (_Float16)_c.w;                           \
    F1[4] = (_Float16)_d2.x; F1[5] = (_Float16)_d2.y;                          \
    F1[6] = (_Float16)_d2.z; F1[7] = (_Float16)_d2.w; }

// 2-MFMA fp16 dist for row-tile rt + 4-VALU key update (verified R15-R17)
#define PROCESS1(nt, rt, F0, F1, ES) {                                         \
    f32x4 acc = {0.f, 0.f, 0.f, 0.f};                                          \
    acc = __builtin_amdgcn_mfma_f32_16x16x32_f16(AH##rt##0, F0, acc, 0, 0, 0); \
    acc = __builtin_amdgcn_mfma_f32_16x16x32_f16(AH##rt##1, F1, acc, 0, 0, 0); \
    unsigned _nn = (unsigned)(nb + ((nt) << 4) + lrow);  /* global code id */  \
    _Pragma("unroll")                                                          \
    for (int i = 0; i < 4; ++i) {      /* C: col(n)=lane&15, row=quad*4+i */   \
        float v = fmaf(-2.f, acc[i], ES);                                      \
        float kf = __uint_as_float((__float_as_uint(v) & 0xFFFFFE00u) | _nn);  \
        m2[rt][i] = __builtin_amdgcn_fmed3f(kf, m1[rt][i], m2[rt][i]);         \
        m1[rt][i] = fminf(m1[rt][i], kf);                                      \
    } }

#define PROCESS2(nt, F0, F1) {                                                 \
    float _es = esq_s[nb + ((nt) << 4) + lrow];                                \
    PROCESS1(nt, 0, F0, F1, _es)                                               \
    PROCESS1(nt, 1, F0, F1, _es) }

__global__ __launch_bounds__(256, 4) void vq_fused_kernel(
    const float* __restrict__ x, const float* __restrict__ embed,
    float* __restrict__ out_q, float* __restrict__ out_idx) {
    __shared__ __align__(16) _Float16 XsH[2][ROWS * XH_STR];     // 9216 B
    __shared__ float Xs32[2][ROWS * X32_STR];                    // 17664 B
    __shared__ float esq_s[VQ_K];                                // 2048 B
    __shared__ unsigned long long row_best[2][ROWS];             // 512 B
    __shared__ int qcnt[2][4];
    __shared__ unsigned short qbuf[4 * QW];                      // 2048 B

    const int t    = threadIdx.x;
    const int n0b  = blockIdx.x * (ROWS * TILES);   // 128 rows per block
    const int b    = n0b >> 12;      // 128 | 4096 -> block stays in one image
    const int hwb  = n0b & 4095;

    const int lane = t & 63;
    const int wave = t >> 6;
    const int lrow = lane & 15;
    const int quad = lane >> 4;
    const int nb   = wave * 128;     // this wave's 128 codes

    const int shw  = t & 31;         // staging: this thread's row-in-tile
    const int sd0  = (t >> 5) * 8;   // staging: this thread's 8 d-values
    const float* xbase = x + (size_t)b * (VQ_D * VQ_HW) + hwb + shw;

    // ---- prologue: issue tile-0 x prefetch FIRST (HBM latency) ----
    float P[8];
#pragma unroll
    for (int dd = 0; dd < 8; ++dd) P[dd] = xbase[(sd0 + dd) * VQ_HW];

    // ---- wave's 128 codes as fp16 B-frags in registers (once) ----
    half8 B00, B01, B10, B11, B20, B21, B30, B31;
    half8 B40, B41, B50, B51, B60, B61, B70, B71;
    LOADBF(0, B00, B01) LOADBF(1, B10, B11)
    LOADBF(2, B20, B21) LOADBF(3, B30, B31)
    LOADBF(4, B40, B41) LOADBF(5, B50, B51)
    LOADBF(6, B60, B61) LOADBF(7, B70, B71)

    // ---- cooperative exact esq into LDS: thread t -> codes t, t+256.
    //      float4 loads; EXACT prep formula (p0..p3 quad-split) ----
#pragma unroll
    for (int h = 0; h < 2; ++h) {
        const int c = t + h * 256;
        const float4* e4 = (const float4*)(embed + (size_t)c * VQ_D);
        float p0 = 0.f, p1 = 0.f, p2 = 0.f, p3 = 0.f;
#pragma unroll
        for (int d4 = 0; d4 < 16; ++d4) {
            float4 ev = e4[d4];
            p0 = fmaf(ev.x, ev.x, p0);
            p1 = fmaf(ev.y, ev.y, p1);
            p2 = fmaf(ev.z, ev.z, p2);
            p3 = fmaf(ev.w, ev.w, p3);
        }
        esq_s[c] = (p0 + p1) + (p2 + p3);
    }
    if (t < ROWS) row_best[0][t] = ~0ull;
    if (t < 4) qcnt[0][t] = ROWS;    // slots 0..31 reserved for row winners
    __syncthreads();   // esq_s + tile-0 trackers ready

    // ---- 4 row-tiles of 32 rows, software-pipelined ----
#pragma unroll 1
    for (int tile = 0; tile < TILES; ++tile) {
        const int cur = tile & 1, nxt = cur ^ 1;
        const int n0  = n0b + tile * ROWS;

        // stage-write P (tile's x rows) -> LDS fp32 + fp16
        {
            half8 H0;
#pragma unroll
            for (int dd = 0; dd < 8; ++dd) {
                Xs32[cur][shw * X32_STR + sd0 + dd] = P[dd];
                H0[dd] = (_Float16)P[dd];
            }
            *(half8*)&XsH[cur][shw * XH_STR + sd0] = H0;
        }
        // issue NEXT tile's x prefetch (regs free; covered by tile body)
        if (tile + 1 < TILES) {
            const float* xn = xbase + (tile + 1) * ROWS;
#pragma unroll
            for (int dd = 0; dd < 8; ++dd) P[dd] = xn[(sd0 + dd) * VQ_HW];
        }
        __syncthreads();   // barrier (a): stage visible

        // reinit NEXT tile's trackers (last read pre-(a) by tile-1 epilogue)
        if (t < ROWS) row_best[nxt][t] = ~0ull;
        if (t < 4) qcnt[nxt][t] = ROWS;

        // A fragments via ds_read_b128: A[m=lrow][k=quad*8+j]
        half8 AH00, AH01, AH10, AH11;
#define LOADA(rt)                                                              \
    AH##rt##0 = *(const half8*)&XsH[cur][(rt*16 + lrow) * XH_STR + quad*8];    \
    AH##rt##1 = *(const half8*)&XsH[cur][(rt*16 + lrow) * XH_STR + 32 + quad*8];
        LOADA(0) LOADA(1)
#undef LOADA

        float m1[2][4], m2[2][4];
#pragma unroll
        for (int rt = 0; rt < 2; ++rt)
#pragma unroll
            for (int i = 0; i < 4; ++i) {
                m1[rt][i] = __uint_as_float(0x7F800000u);   // +inf (low 9b 0)
                m2[rt][i] = __uint_as_float(0x7F800000u);
            }

        // hot loop: 32 MFMA + 256 VALU, B from regs, es from LDS
        PROCESS2(0, B00, B01)
        PROCESS2(1, B10, B11)
        PROCESS2(2, B20, B21)
        PROCESS2(3, B30, B31)
        PROCESS2(4, B40, B41)
        PROCESS2(5, B50, B51)
        PROCESS2(6, B60, B61)
        PROCESS2(7, B70, B71)

        // wave-local row-min over the 16 n-lanes (per rt,i)
        float g1[2][4];
#pragma unroll
        for (int rt = 0; rt < 2; ++rt)
#pragma unroll
            for (int i = 0; i < 4; ++i) g1[rt][i] = m1[rt][i];
#pragma unroll
        for (int s = 1; s <= 8; s <<= 1)
#pragma unroll
            for (int rt = 0; rt < 2; ++rt)
#pragma unroll
                for (int i = 0; i < 4; ++i)
                    g1[rt][i] = fminf(g1[rt][i], __shfl_xor(g1[rt][i], s));

        // push candidates: winner -> fixed slot m; near-ties -> slots 32+
#pragma unroll
        for (int rt = 0; rt < 2; ++rt)
#pragma unroll
            for (int i = 0; i < 4; ++i) {
                int m = rt * 16 + quad * 4 + i;        // block-local row 0..31
                float thr = clr9(g1[rt][i]) + EPS;
                if (m1[rt][i] == g1[rt][i]) {
                    qbuf[wave * QW + m] = (unsigned short)
                        (((unsigned)m << 9) |
                         (__float_as_uint(m1[rt][i]) & 511u));
                } else if (clr9(m1[rt][i]) <= thr) {
                    int id = atomicAdd(&qcnt[cur][wave], 1);
                    if (id < QW)
                        qbuf[wave * QW + id] = (unsigned short)
                            (((unsigned)m << 9) |
                             (__float_as_uint(m1[rt][i]) & 511u));
                }
                if (clr9(m2[rt][i]) <= thr) {
                    int id = atomicAdd(&qcnt[cur][wave], 1);
                    if (id < QW)
                        qbuf[wave * QW + id] = (unsigned short)
                            (((unsigned)m << 9) |
                             (__float_as_uint(m2[rt][i]) & 511u));
                }
            }
        asm volatile("s_waitcnt lgkmcnt(0)");   // wave-local queue visible

        // exact fp32 recheck (same fmaf order as R1 kernel), wave-local
        int qc = atomicAdd(&qcnt[cur][wave], 0);
        if (qc > QW) qc = QW;
        for (int qi = lane; qi < qc; qi += 64) {
            unsigned e = qbuf[wave * QW + qi];
            int m = (int)(e >> 9), n = (int)(e & 511u);
            const float4* er = (const float4*)(embed + n * VQ_D);
            const float* xr = &Xs32[cur][m * X32_STR];
            float dot = 0.f;
#pragma unroll
            for (int d4 = 0; d4 < 16; ++d4) {
                float4 ev = er[d4];
                dot = fmaf(xr[4 * d4 + 0], ev.x, dot);
                dot = fmaf(xr[4 * d4 + 1], ev.y, dot);
                dot = fmaf(xr[4 * d4 + 2], ev.z, dot);
                dot = fmaf(xr[4 * d4 + 3], ev.w, dot);
            }
            float v = fmaf(-2.f, dot, esq_s[n]);
            unsigned long long key =
                (((unsigned long long)fenc(v)) << 32) | (unsigned)n;
            atomicMin(&row_best[cur][m], key); // exact; tie -> smaller n
        }
        __syncthreads();   // barrier (b): all waves' rechecks done

        // epilogue: indices + fully-coalesced quantized rows
        if (t < ROWS)
            out_idx[n0 + t] = (float)(unsigned)(row_best[cur][t] & 0xffffffffu);

#pragma unroll
        for (int it = 0; it < 2; ++it) {
            int o   = it * 1024 + t * 4;   // 32 rows x 64 floats, contiguous
            int row = o >> 6;
            int col = o & 63;
            unsigned k = (unsigned)(row_best[cur][row] & 0xffffffffu);
            float4 val = *(const float4*)(embed + k * VQ_D + col);
            *(float4*)(out_q + (size_t)n0 * VQ_D + o) = val;
        }
        // no barrier: next iter writes the OTHER X buffer; row_best/qcnt
        // reinit for [nxt] happens after the next barrier (a).
    }
}

extern "C" void kernel_launch(void* const* d_in, const int* in_sizes, int n_in,
                              void* d_out, int out_size, void* d_ws, size_t ws_size,
                              hipStream_t stream) {
    const float* x     = (const float*)d_in[0];
    const float* embed = (const float*)d_in[1];
    float* out_q   = (float*)d_out;
    float* out_idx = (float*)d_out + (size_t)VQ_N * VQ_D;

    vq_fused_kernel<<<VQ_N / (ROWS * TILES), 256, 0, stream>>>(
        x, embed, out_q, out_idx);
}

// Round 7
// 133.560 us; speedup vs baseline: 2.4853x; 2.4853x over previous
//
#include <hip/hip_runtime.h>

// VQ via MFMA: x (32,64,64,64) fp32 NCHW, embed (512,64) fp32.
// fp16 MFMA approx dists (err ~0.18 << EPS 0.5), exact fp32 recheck of
// near-min candidates (bit-identical dot+esq formulas) -> exact argmin.
//
// R18 post-mortem: launch_bounds(256,4) forced VGPR 64 << ~140 live set ->
// 280MB/iter scratch traffic (WRITE 313MB, FETCH 310MB), HBM-bound 267us.
// Pipeline theory NOT tested (experiment invalidated by spill tripwire).
// Calibration gained: chip sustained 2.39 TB/s -> clocks/fabric healthy;
// the 65us wall of R15-R17 is real idle time.
//
// R19 = R18 structure, spill removed: launch_bounds(256,2) (R17-proven:
// VGPR 128, no spill), TILES=8/grid=512 (R17-identical shape). Only delta
// vs R17's 65us is the PIPELINE: P-reg async-stage (tile t+1's x loads
// issued under tile t's body), double-buffered X, barrier 3 deleted
// (2 barriers/tile). Decisive test of the intra-block latency chain.
// Predict: VGPR 130-160, WRITE 33.3MB (tripwire), LDS 31.5KB, occ 18-25%.
// Theory right -> dur 42-52us. dur 62-67 -> theory dead; wall is a
// work-shape latency floor (invariant to occ/MFMA/blocks/dispatch/
// residency/pipelining) -> declare roofline-of-structure.

#define VQ_N 131072
#define VQ_D 64
#define VQ_K 512
#define VQ_HW 4096
#define ROWS 32          // rows per tile
#define TILES 8          // row-tiles per block; grid = N/(ROWS*TILES) = 512
#define EPS 0.5f         // prune margin; fp16 worst-case err ~0.18, typ ~0.01
#define QW 256           // queue entries per wave (slots 0..31 = row winners)
#define XH_STR 72        // f16/row (64+8 pad), 144B stride (16B-aligned)
#define X32_STR 69       // floats/row: ODD -> conflict-free staging writes

typedef __attribute__((ext_vector_type(8))) _Float16 half8;
typedef __attribute__((ext_vector_type(4))) float f32x4;

// order-preserving float->uint for the exact-recheck u64 key
static __device__ __forceinline__ unsigned fenc(float f) {
    unsigned u = __float_as_uint(f);
    return u ^ ((unsigned)(((int)u) >> 31) | 0x80000000u);
}
// clear low 9 mantissa bits (decode of embedded-index float keys)
static __device__ __forceinline__ float clr9(float f) {
    return __uint_as_float(__float_as_uint(f) & 0xFFFFFE00u);
}

// build B fragment pair for code-tile nt from embed fp32 (RTE casts)
#define LOADBF(nt, F0, F1) {                                                   \
    const float* _er = embed + (size_t)(nb + ((nt) << 4) + lrow) * VQ_D        \
                       + (quad << 3);                                          \
    float4 _a = *(const float4*)_er;                                           \
    float4 _b2 = *(const float4*)(_er + 4);                                    \
    float4 _c = *(const float4*)(_er + 32);                                    \
    float4 _d2 = *(const float4*)(_er + 36);                                   \
    F0[0] = (_Float16)_a.x;  F0[1] = (_Float16)_a.y;                           \
    F0[2] = (_Float16)_a.z;  F0[3] = (_Float16)_a.w;                           \
    F0[4] = (_Float16)_b2.x; F0[5] = (_Float16)_b2.y;                          \
    F0[6] = (_Float16)_b2.z; F0[7] = (_Float16)_b2.w;                          \
    F1[0] = (_Float16)_c.x;  F1[1] = (_Float16)_c.y;                           \
    F1[2] = (_Float16)_c.z;  F1[3] = (_Float16)_c.w;                           \
    F1[4] = (_Float16)_d2.x; F1[5] = (_Float16)_d2.y;                          \
    F1[6] = (_Float16)_d2.z; F1[7] = (_Float16)_d2.w; }

// 2-MFMA fp16 dist for row-tile rt + 4-VALU key update (verified R15-R17)
#define PROCESS1(nt, rt, F0, F1, ES) {                                         \
    f32x4 acc = {0.f, 0.f, 0.f, 0.f};                                          \
    acc = __builtin_amdgcn_mfma_f32_16x16x32_f16(AH##rt##0, F0, acc, 0, 0, 0); \
    acc = __builtin_amdgcn_mfma_f32_16x16x32_f16(AH##rt##1, F1, acc, 0, 0, 0); \
    unsigned _nn = (unsigned)(nb + ((nt) << 4) + lrow);  /* global code id */  \
    _Pragma("unroll")                                                          \
    for (int i = 0; i < 4; ++i) {      /* C: col(n)=lane&15, row=quad*4+i */   \
        float v = fmaf(-2.f, acc[i], ES);                                      \
        float kf = __uint_as_float((__float_as_uint(v) & 0xFFFFFE00u) | _nn);  \
        m2[rt][i] = __builtin_amdgcn_fmed3f(kf, m1[rt][i], m2[rt][i]);         \
        m1[rt][i] = fminf(m1[rt][i], kf);                                      \
    } }

#define PROCESS2(nt, F0, F1) {                                                 \
    float _es = esq_s[nb + ((nt) << 4) + lrow];                                \
    PROCESS1(nt, 0, F0, F1, _es)                                               \
    PROCESS1(nt, 1, F0, F1, _es) }

__global__ __launch_bounds__(256, 2) void vq_fused_kernel(
    const float* __restrict__ x, const float* __restrict__ embed,
    float* __restrict__ out_q, float* __restrict__ out_idx) {
    __shared__ __align__(16) _Float16 XsH[2][ROWS * XH_STR];     // 9216 B
    __shared__ float Xs32[2][ROWS * X32_STR];                    // 17664 B
    __shared__ float esq_s[VQ_K];                                // 2048 B
    __shared__ unsigned long long row_best[2][ROWS];             // 512 B
    __shared__ int qcnt[2][4];
    __shared__ unsigned short qbuf[4 * QW];                      // 2048 B

    const int t    = threadIdx.x;
    const int n0b  = blockIdx.x * (ROWS * TILES);   // 256 rows per block
    const int b    = n0b >> 12;      // 256 | 4096 -> block stays in one image
    const int hwb  = n0b & 4095;

    const int lane = t & 63;
    const int wave = t >> 6;
    const int lrow = lane & 15;
    const int quad = lane >> 4;
    const int nb   = wave * 128;     // this wave's 128 codes

    const int shw  = t & 31;         // staging: this thread's row-in-tile
    const int sd0  = (t >> 5) * 8;   // staging: this thread's 8 d-values
    const float* xbase = x + (size_t)b * (VQ_D * VQ_HW) + hwb + shw;

    // ---- prologue: issue tile-0 x prefetch FIRST (HBM latency) ----
    float P[8];
#pragma unroll
    for (int dd = 0; dd < 8; ++dd) P[dd] = xbase[(sd0 + dd) * VQ_HW];

    // ---- wave's 128 codes as fp16 B-frags in registers (once) ----
    half8 B00, B01, B10, B11, B20, B21, B30, B31;
    half8 B40, B41, B50, B51, B60, B61, B70, B71;
    LOADBF(0, B00, B01) LOADBF(1, B10, B11)
    LOADBF(2, B20, B21) LOADBF(3, B30, B31)
    LOADBF(4, B40, B41) LOADBF(5, B50, B51)
    LOADBF(6, B60, B61) LOADBF(7, B70, B71)

    // ---- cooperative exact esq into LDS: thread t -> codes t, t+256.
    //      float4 loads; EXACT prep formula (p0..p3 quad-split) ----
#pragma unroll
    for (int h = 0; h < 2; ++h) {
        const int c = t + h * 256;
        const float4* e4 = (const float4*)(embed + (size_t)c * VQ_D);
        float p0 = 0.f, p1 = 0.f, p2 = 0.f, p3 = 0.f;
#pragma unroll
        for (int d4 = 0; d4 < 16; ++d4) {
            float4 ev = e4[d4];
            p0 = fmaf(ev.x, ev.x, p0);
            p1 = fmaf(ev.y, ev.y, p1);
            p2 = fmaf(ev.z, ev.z, p2);
            p3 = fmaf(ev.w, ev.w, p3);
        }
        esq_s[c] = (p0 + p1) + (p2 + p3);
    }
    if (t < ROWS) row_best[0][t] = ~0ull;
    if (t < 4) qcnt[0][t] = ROWS;    // slots 0..31 reserved for row winners
    __syncthreads();   // esq_s + tile-0 trackers ready

    // ---- 8 row-tiles of 32 rows, software-pipelined ----
#pragma unroll 1
    for (int tile = 0; tile < TILES; ++tile) {
        const int cur = tile & 1, nxt = cur ^ 1;
        const int n0  = n0b + tile * ROWS;

        // stage-write P (tile's x rows) -> LDS fp32 + fp16
        {
            half8 H0;
#pragma unroll
            for (int dd = 0; dd < 8; ++dd) {
                Xs32[cur][shw * X32_STR + sd0 + dd] = P[dd];
                H0[dd] = (_Float16)P[dd];
            }
            *(half8*)&XsH[cur][shw * XH_STR + sd0] = H0;
        }
        // issue NEXT tile's x prefetch (regs free; covered by tile body)
        if (tile + 1 < TILES) {
            const float* xn = xbase + (tile + 1) * ROWS;
#pragma unroll
            for (int dd = 0; dd < 8; ++dd) P[dd] = xn[(sd0 + dd) * VQ_HW];
        }
        __syncthreads();   // barrier (a): stage visible

        // reinit NEXT tile's trackers (prev epilogue done: all threads
        // passed barrier (a) after it in program order)
        if (t < ROWS) row_best[nxt][t] = ~0ull;
        if (t < 4) qcnt[nxt][t] = ROWS;

        // A fragments via ds_read_b128: A[m=lrow][k=quad*8+j]
        half8 AH00, AH01, AH10, AH11;
#define LOADA(rt)                                                              \
    AH##rt##0 = *(const half8*)&XsH[cur][(rt*16 + lrow) * XH_STR + quad*8];    \
    AH##rt##1 = *(const half8*)&XsH[cur][(rt*16 + lrow) * XH_STR + 32 + quad*8];
        LOADA(0) LOADA(1)
#undef LOADA

        float m1[2][4], m2[2][4];
#pragma unroll
        for (int rt = 0; rt < 2; ++rt)
#pragma unroll
            for (int i = 0; i < 4; ++i) {
                m1[rt][i] = __uint_as_float(0x7F800000u);   // +inf (low 9b 0)
                m2[rt][i] = __uint_as_float(0x7F800000u);
            }

        // hot loop: 32 MFMA + 256 VALU, B from regs, es from LDS
        PROCESS2(0, B00, B01)
        PROCESS2(1, B10, B11)
        PROCESS2(2, B20, B21)
        PROCESS2(3, B30, B31)
        PROCESS2(4, B40, B41)
        PROCESS2(5, B50, B51)
        PROCESS2(6, B60, B61)
        PROCESS2(7, B70, B71)

        // wave-local row-min over the 16 n-lanes (per rt,i)
        float g1[2][4];
#pragma unroll
        for (int rt = 0; rt < 2; ++rt)
#pragma unroll
            for (int i = 0; i < 4; ++i) g1[rt][i] = m1[rt][i];
#pragma unroll
        for (int s = 1; s <= 8; s <<= 1)
#pragma unroll
            for (int rt = 0; rt < 2; ++rt)
#pragma unroll
                for (int i = 0; i < 4; ++i)
                    g1[rt][i] = fminf(g1[rt][i], __shfl_xor(g1[rt][i], s));

        // push candidates: winner -> fixed slot m; near-ties -> slots 32+
#pragma unroll
        for (int rt = 0; rt < 2; ++rt)
#pragma unroll
            for (int i = 0; i < 4; ++i) {
                int m = rt * 16 + quad * 4 + i;        // block-local row 0..31
                float thr = clr9(g1[rt][i]) + EPS;
                if (m1[rt][i] == g1[rt][i]) {
                    qbuf[wave * QW + m] = (unsigned short)
                        (((unsigned)m << 9) |
                         (__float_as_uint(m1[rt][i]) & 511u));
                } else if (clr9(m1[rt][i]) <= thr) {
                    int id = atomicAdd(&qcnt[cur][wave], 1);
                    if (id < QW)
                        qbuf[wave * QW + id] = (unsigned short)
                            (((unsigned)m << 9) |
                             (__float_as_uint(m1[rt][i]) & 511u));
                }
                if (clr9(m2[rt][i]) <= thr) {
                    int id = atomicAdd(&qcnt[cur][wave], 1);
                    if (id < QW)
                        qbuf[wave * QW + id] = (unsigned short)
                            (((unsigned)m << 9) |
                             (__float_as_uint(m2[rt][i]) & 511u));
                }
            }
        asm volatile("s_waitcnt lgkmcnt(0)");   // wave-local queue visible

        // exact fp32 recheck (same fmaf order as R1 kernel), wave-local
        int qc = atomicAdd(&qcnt[cur][wave], 0);
        if (qc > QW) qc = QW;
        for (int qi = lane; qi < qc; qi += 64) {
            unsigned e = qbuf[wave * QW + qi];
            int m = (int)(e >> 9), n = (int)(e & 511u);
            const float4* er = (const float4*)(embed + n * VQ_D);
            const float* xr = &Xs32[cur][m * X32_STR];
            float dot = 0.f;
#pragma unroll
            for (int d4 = 0; d4 < 16; ++d4) {
                float4 ev = er[d4];
                dot = fmaf(xr[4 * d4 + 0], ev.x, dot);
                dot = fmaf(xr[4 * d4 + 1], ev.y, dot);
                dot = fmaf(xr[4 * d4 + 2], ev.z, dot);
                dot = fmaf(xr[4 * d4 + 3], ev.w, dot);
            }
            float v = fmaf(-2.f, dot, esq_s[n]);
            unsigned long long key =
                (((unsigned long long)fenc(v)) << 32) | (unsigned)n;
            atomicMin(&row_best[cur][m], key); // exact; tie -> smaller n
        }
        __syncthreads();   // barrier (b): all waves' rechecks done

        // epilogue: indices + fully-coalesced quantized rows
        if (t < ROWS)
            out_idx[n0 + t] = (float)(unsigned)(row_best[cur][t] & 0xffffffffu);

#pragma unroll
        for (int it = 0; it < 2; ++it) {
            int o   = it * 1024 + t * 4;   // 32 rows x 64 floats, contiguous
            int row = o >> 6;
            int col = o & 63;
            unsigned k = (unsigned)(row_best[cur][row] & 0xffffffffu);
            float4 val = *(const float4*)(embed + k * VQ_D + col);
            *(float4*)(out_q + (size_t)n0 * VQ_D + o) = val;
        }
        // no barrier: next iter writes the OTHER X buffer; row_best/qcnt
        // reinit for [nxt] happens after the next barrier (a).
    }
}

extern "C" void kernel_launch(void* const* d_in, const int* in_sizes, int n_in,
                              void* d_out, int out_size, void* d_ws, size_t ws_size,
                              hipStream_t stream) {
    const float* x     = (const float*)d_in[0];
    const float* embed = (const float*)d_in[1];
    float* out_q   = (float*)d_out;
    float* out_idx = (float*)d_out + (size_t)VQ_N * VQ_D;

    vq_fused_kernel<<<VQ_N / (ROWS * TILES), 256, 0, stream>>>(
        x, embed, out_q, out_idx);
}